// Round 2
// baseline (54.953 us; speedup 1.0000x reference)
//
#include <hip/hip_runtime.h>
#include <hip/hip_bf16.h>

// Problem constants (from reference)
#define BATCH    1048576
#define NTILES   (BATCH / 16)     // 65536 wave-tiles of 16 rows
#define TILES_PER_WAVE 8          // 8192 waves x 8 tiles = 65536
#define SCALE1   3.0f             // scale_factor + 1
#define CMIN    -10.0f
#define CMAX     10.0f

typedef __attribute__((ext_vector_type(8))) short  bf16x8;  // 8 bf16 = 4 VGPRs
typedef __attribute__((ext_vector_type(4))) float  f32x4;   // MFMA accumulator

__device__ __forceinline__ short f2bf(float f) {
    __hip_bfloat16 h = __float2bfloat16(f);   // RNE, lowers to v_cvt
    return __builtin_bit_cast(short, h);
}

__device__ __forceinline__ bf16x8 pack8(float4 a, float4 b) {
    bf16x8 f;
    f[0] = f2bf(a.x); f[1] = f2bf(a.y); f[2] = f2bf(a.z); f[3] = f2bf(a.w);
    f[4] = f2bf(b.x); f[5] = f2bf(b.y); f[6] = f2bf(b.z); f[7] = f2bf(b.w);
    return f;
}

// z = x @ W^T (bf16 MFMA), v = clamp(3z), lse = log(sum exp v), out = mish(lse)
// No LDS: A-fragments (row = l15, k = 8*l4 + e) load directly from global,
// fully coalesced (lanes {l15, l15+16, l15+32, l15+48} cover each 256B row).
__global__ __launch_bounds__(256, 4)
void fused_lse_mish(const float* __restrict__ x,
                    const float* __restrict__ W,
                    float* __restrict__ out) {
    const int tid  = threadIdx.x;
    const int lane = tid & 63;
    const int l15  = lane & 15;   // 0..15  -> A row within tile / B col
    const int l4   = lane >> 4;   // 0..3   -> A k-group / B k-group

    // ---- Preload W^T fragments (held in registers for the whole kernel).
    // B-frag(t,s): lane holds B[k][n], n = 16t + l15, k = 32s + 8*l4 + e
    // B[j][n] = W[n][j]  ->  W row (16t + l15), cols 32s + 8*l4 .. +7 (contiguous)
    bf16x8 bfrag[4][2];
    #pragma unroll
    for (int t = 0; t < 4; ++t) {
        const float* wp = W + (t * 16 + l15) * 64 + l4 * 8;
        #pragma unroll
        for (int s = 0; s < 2; ++s) {
            float4 w0 = *reinterpret_cast<const float4*>(wp + s * 32);
            float4 w1 = *reinterpret_cast<const float4*>(wp + s * 32 + 4);
            bfrag[t][s] = pack8(w0, w1);
        }
    }

    const int gwave = (int)((blockIdx.x * blockDim.x + tid) >> 6);

    // Each wave streams 8 consecutive 16x64 tiles = 32 KB contiguous.
    const float* p = x + (size_t)gwave * (TILES_PER_WAVE * 1024)
                       + l15 * 64 + l4 * 8;

    // prologue: issue tile 0's loads
    float4 f0 = *reinterpret_cast<const float4*>(p);
    float4 f1 = *reinterpret_cast<const float4*>(p + 4);
    float4 f2 = *reinterpret_cast<const float4*>(p + 32);
    float4 f3 = *reinterpret_cast<const float4*>(p + 36);

    for (int i = 0; i < TILES_PER_WAVE; ++i) {
        // ---- prefetch tile i+1 (issued before this tile's compute chain)
        float4 g0, g1, g2, g3;
        if (i < TILES_PER_WAVE - 1) {
            const float* q = p + (i + 1) * 1024;
            g0 = *reinterpret_cast<const float4*>(q);
            g1 = *reinterpret_cast<const float4*>(q + 4);
            g2 = *reinterpret_cast<const float4*>(q + 32);
            g3 = *reinterpret_cast<const float4*>(q + 36);
        }

        // ---- A fragments: fp32 -> bf16 in registers
        bf16x8 a0 = pack8(f0, f1);   // k 0..31
        bf16x8 a1 = pack8(f2, f3);   // k 32..63

        // ---- 8 MFMAs: z[16][64] ; acc[t] covers hid cols 16t..16t+15
        f32x4 acc[4];
        #pragma unroll
        for (int t = 0; t < 4; ++t) {
            f32x4 z; z[0] = 0.f; z[1] = 0.f; z[2] = 0.f; z[3] = 0.f;
            z = __builtin_amdgcn_mfma_f32_16x16x32_bf16(a0, bfrag[t][0], z, 0, 0, 0);
            z = __builtin_amdgcn_mfma_f32_16x16x32_bf16(a1, bfrag[t][1], z, 0, 0, 0);
            acc[t] = z;
        }

        // ---- epilogue: C/D layout col = l15 (+16t), row = 4*l4 + i
        // v in [-10,10] -> exp-sum without max subtraction is safe in fp32
        float s[4];
        #pragma unroll
        for (int r = 0; r < 4; ++r) {
            float sum = 0.f;
            #pragma unroll
            for (int t = 0; t < 4; ++t) {
                float v = acc[t][r] * SCALE1;
                v = fminf(fmaxf(v, CMIN), CMAX);
                sum += __expf(v);
            }
            // reduce across the 16-lane group (row 4*l4 + r lives in lanes 16*l4..+15)
            sum += __shfl_xor(sum, 1);
            sum += __shfl_xor(sum, 2);
            sum += __shfl_xor(sum, 4);
            sum += __shfl_xor(sum, 8);
            s[r] = sum;
        }

        // lane 16*q + j (j<4) writes row tile*16 + 4*q + j
        float sv = (l15 == 0) ? s[0] : (l15 == 1) ? s[1] : (l15 == 2) ? s[2] : s[3];
        float lse = __logf(sv);
        float sp  = __logf(1.f + __expf(lse));          // softplus(lse)
        float e2  = __expf(2.f * sp);
        float th  = 1.f - 2.f / (e2 + 1.f);             // tanh(sp)
        if (l15 < 4) out[(gwave * TILES_PER_WAVE + i) * 16 + l4 * 4 + l15] = lse * th;

        // rotate pipeline
        f0 = g0; f1 = g1; f2 = g2; f3 = g3;
    }
}

extern "C" void kernel_launch(void* const* d_in, const int* in_sizes, int n_in,
                              void* d_out, int out_size, void* d_ws, size_t ws_size,
                              hipStream_t stream) {
    const float* x = (const float*)d_in[0];   // [BATCH, 64] fp32
    const float* W = (const float*)d_in[1];   // [64, 64]   fp32
    float* out = (float*)d_out;               // [BATCH] fp32 (B x 1)

    dim3 grid(2048), block(256);              // 8192 waves x 8 tiles
    hipLaunchKernelGGL(fused_lse_mish, grid, block, 0, stream, x, W, out);
}

// Round 3
// 48.009 us; speedup vs baseline: 1.1446x; 1.1446x over previous
//
#include <hip/hip_runtime.h>
#include <hip/hip_bf16.h>

// Problem constants (from reference)
#define BATCH    1048576
#define NTILES   (BATCH / 16)     // 65536 wave-tiles of 16 batch rows
#define TPW      8                // tiles per wave; 8192 waves x 8 = 65536
#define SCALE1   3.0f             // scale_factor + 1
#define CMIN    -10.0f
#define CMAX     10.0f

typedef __attribute__((ext_vector_type(8))) short  bf16x8;  // 8 bf16 = 4 VGPRs
typedef __attribute__((ext_vector_type(4))) float  f32x4;   // MFMA accumulator

__device__ __forceinline__ short f2bf(float f) {
    __hip_bfloat16 h = __float2bfloat16(f);   // RNE v_cvt
    return __builtin_bit_cast(short, h);
}

// D = W @ x^T  (m=hid, n=batch, k=in), bf16 MFMA.
// C/D layout: col = lane&15 = BATCH, row = 4*(lane>>4)+i = hid -> the LSE
// reduction over hid is 15 VALU adds + 2 shfl_xor (vs 16 shfl for x@W^T).
__global__ __launch_bounds__(256, 4)
void fused_lse_mish(const float* __restrict__ x,
                    const float* __restrict__ W,
                    float* __restrict__ out) {
    // wave-private DOUBLE-buffered bf16 staging (16 rows x 64 cols = 2KB each)
    __shared__ alignas(16) unsigned char lds[4 * 2 * 2048];

    const int tid  = threadIdx.x;
    const int wid  = tid >> 6;
    const int lane = tid & 63;
    const int l15  = lane & 15;   // 0..15
    const int l4   = lane >> 4;   // 0..3
    unsigned char* wlds = lds + wid * 4096;

    // ---- A operand = W (m=hid, k=in), register-resident for whole kernel.
    // A-frag(t,s): lane holds A[m=16t+l15][k=32s+8*l4+e] = W row 16t+l15 (contiguous)
    bf16x8 wfrag[4][2];
    #pragma unroll
    for (int t = 0; t < 4; ++t) {
        const float* wp = W + (t * 16 + l15) * 64 + l4 * 8;
        #pragma unroll
        for (int s = 0; s < 2; ++s) {
            float4 w0 = *reinterpret_cast<const float4*>(wp + s * 32);
            float4 w1 = *reinterpret_cast<const float4*>(wp + s * 32 + 4);
            bf16x8 f;
            f[0] = f2bf(w0.x); f[1] = f2bf(w0.y); f[2] = f2bf(w0.z); f[3] = f2bf(w0.w);
            f[4] = f2bf(w1.x); f[5] = f2bf(w1.y); f[6] = f2bf(w1.z); f[7] = f2bf(w1.w);
            wfrag[t][s] = f;
        }
    }

    // B-frag read addrs (B[k][n]=x[n][k]: row = l15, k-bytes l4*16 (+64))
    // swizzle phys = row*128 + (colbyte ^ ((row&7)<<4)) -> no 16-way conflicts
    const unsigned rswz = (unsigned)((l15 & 7) << 4);
    const unsigned ra0  = (unsigned)(l15 * 128) + (((unsigned)(l4 * 16))      ^ rswz);
    const unsigned ra1  = (unsigned)(l15 * 128) + (((unsigned)(64 + l4 * 16)) ^ rswz);

    const int gwave = (int)((blockIdx.x * blockDim.x + tid) >> 6);
    const float* xp = x + (size_t)gwave * (TPW * 1024);   // 8 tiles, contiguous 32KB

    // ---- stage tile 0 (dense: each load instr = 1KB contiguous across wave)
    {
        unsigned char* b0 = wlds;
        #pragma unroll
        for (int it = 0; it < 4; ++it) {
            const int r = it * 4 + l4;
            float4 v = *reinterpret_cast<const float4*>(xp + r * 64 + l15 * 4);
            short4 b;
            b.x = f2bf(v.x); b.y = f2bf(v.y); b.z = f2bf(v.z); b.w = f2bf(v.w);
            unsigned wa = (unsigned)(r * 128) +
                          (((unsigned)(l15 * 8)) ^ ((unsigned)((r & 7) << 4)));
            *reinterpret_cast<short4*>(b0 + wa) = b;
        }
    }

    for (int i = 0; i < TPW; ++i) {
        unsigned char* cur = wlds + ((i & 1) ? 2048 : 0);
        unsigned char* nxt = wlds + ((i & 1) ? 0 : 2048);

        // ---- issue tile i+1 global loads FIRST (land under MFMA+epilogue)
        float4 g0, g1, g2, g3;
        if (i + 1 < TPW) {
            const float* q = xp + (i + 1) * 1024;
            g0 = *reinterpret_cast<const float4*>(q + (0 * 4 + l4) * 64 + l15 * 4);
            g1 = *reinterpret_cast<const float4*>(q + (1 * 4 + l4) * 64 + l15 * 4);
            g2 = *reinterpret_cast<const float4*>(q + (2 * 4 + l4) * 64 + l15 * 4);
            g3 = *reinterpret_cast<const float4*>(q + (3 * 4 + l4) * 64 + l15 * 4);
        }

        // ---- B fragments from LDS, then 8 MFMAs
        bf16x8 b0 = *reinterpret_cast<const bf16x8*>(cur + ra0);  // k 0..31
        bf16x8 b1 = *reinterpret_cast<const bf16x8*>(cur + ra1);  // k 32..63

        f32x4 acc[4];
        #pragma unroll
        for (int t = 0; t < 4; ++t) {
            f32x4 z; z[0] = 0.f; z[1] = 0.f; z[2] = 0.f; z[3] = 0.f;
            z = __builtin_amdgcn_mfma_f32_16x16x32_bf16(wfrag[t][0], b0, z, 0, 0, 0);
            z = __builtin_amdgcn_mfma_f32_16x16x32_bf16(wfrag[t][1], b1, z, 0, 0, 0);
            acc[t] = z;
        }

        // ---- epilogue: lane holds 16 hid-values of batch col l15
        // v in [-10,10] -> exp-sum without max subtraction is safe in fp32
        float sum = 0.f;
        #pragma unroll
        for (int t = 0; t < 4; ++t) {
            #pragma unroll
            for (int r = 0; r < 4; ++r) {
                float v = acc[t][r] * SCALE1;
                v = fminf(fmaxf(v, CMIN), CMAX);
                sum += __expf(v);
            }
        }
        // combine the 4 lane-groups holding the other 48 hid-values
        sum += __shfl_xor(sum, 16);
        sum += __shfl_xor(sum, 32);

        float lse = __logf(sum);
        float sp  = __logf(1.f + __expf(lse));          // softplus(lse)
        float e2  = __expf(2.f * sp);
        float th  = 1.f - 2.f / (e2 + 1.f);             // tanh(sp)
        float res = lse * th;

        // ---- stage tile i+1 (vmcnt wait lands here, after long VALU chain)
        if (i + 1 < TPW) {
            #pragma unroll
            for (int it = 0; it < 4; ++it) {
                const int r = it * 4 + l4;
                float4 v = (it == 0) ? g0 : (it == 1) ? g1 : (it == 2) ? g2 : g3;
                short4 b;
                b.x = f2bf(v.x); b.y = f2bf(v.y); b.z = f2bf(v.z); b.w = f2bf(v.w);
                unsigned wa = (unsigned)(r * 128) +
                              (((unsigned)(l15 * 8)) ^ ((unsigned)((r & 7) << 4)));
                *reinterpret_cast<short4*>(nxt + wa) = b;
            }
        }

        if (lane < 16) out[(gwave * TPW + i) * 16 + l15] = res;
    }
}

extern "C" void kernel_launch(void* const* d_in, const int* in_sizes, int n_in,
                              void* d_out, int out_size, void* d_ws, size_t ws_size,
                              hipStream_t stream) {
    const float* x = (const float*)d_in[0];   // [BATCH, 64] fp32
    const float* W = (const float*)d_in[1];   // [64, 64]   fp32
    float* out = (float*)d_out;               // [BATCH] fp32 (B x 1)

    dim3 grid(2048), block(256);              // 8192 waves x 8 tiles
    hipLaunchKernelGGL(fused_lse_mish, grid, block, 0, stream, x, W, out);
}

// Round 4
// 47.226 us; speedup vs baseline: 1.1636x; 1.0166x over previous
//
#include <hip/hip_runtime.h>
#include <hip/hip_bf16.h>

// Problem constants (from reference)
#define BATCH    1048576
#define TPW      8                // tiles per wave; 8192 waves x 8 = 65536 tiles
#define K_SCALE  4.32808512266689f   // 3.0 * log2(e): fold scale into exp2 domain
#define K_CLAMP  14.4269504088896f   // 10.0 * log2(e)

typedef __attribute__((ext_vector_type(8))) short  bf16x8;  // 8 bf16 = 4 VGPRs
typedef __attribute__((ext_vector_type(4))) float  f32x4;   // MFMA accumulator

__device__ __forceinline__ short f2bf(float f) {
    __hip_bfloat16 h = __float2bfloat16(f);   // RNE v_cvt
    return __builtin_bit_cast(short, h);
}

// D = W @ x^T (m=hid, n=batch, k=in), bf16 MFMA.
// C/D layout: col = lane&15 = batch, row = 4*(lane>>4)+i = hid -> LSE over hid
// is 15 VALU adds + 2 shfl_xor. 2-deep load pipeline: at iter i issue loads
// for tile i+2, stage (vmcnt-wait) loads for tile i+1, compute tile i.
__global__ __launch_bounds__(256, 4)
void fused_lse_mish(const float* __restrict__ x,
                    const float* __restrict__ W,
                    float* __restrict__ out) {
    // wave-private double-buffered bf16 staging (16 x 64 = 2KB per buffer)
    __shared__ alignas(16) unsigned char lds[4 * 2 * 2048];

    const int tid  = threadIdx.x;
    const int wid  = tid >> 6;
    const int lane = tid & 63;
    const int l15  = lane & 15;   // 0..15
    const int l4   = lane >> 4;   // 0..3
    unsigned char* wlds = lds + wid * 4096;

    // ---- A operand = W (m=hid, k=in), register-resident.
    // A-frag(t,s): lane holds A[m=16t+l15][k=32s+8*l4+e] (W row-contiguous)
    bf16x8 wfrag[4][2];
    #pragma unroll
    for (int t = 0; t < 4; ++t) {
        const float* wp = W + (t * 16 + l15) * 64 + l4 * 8;
        #pragma unroll
        for (int s = 0; s < 2; ++s) {
            float4 w0 = *reinterpret_cast<const float4*>(wp + s * 32);
            float4 w1 = *reinterpret_cast<const float4*>(wp + s * 32 + 4);
            bf16x8 f;
            f[0] = f2bf(w0.x); f[1] = f2bf(w0.y); f[2] = f2bf(w0.z); f[3] = f2bf(w0.w);
            f[4] = f2bf(w1.x); f[5] = f2bf(w1.y); f[6] = f2bf(w1.z); f[7] = f2bf(w1.w);
            wfrag[t][s] = f;
        }
    }

    // B-frag read addrs (B[k][n]=x[n][k]: row = l15, k-bytes l4*16 (+64)),
    // swizzled: phys = row*128 + (colbyte ^ ((row&7)<<4))
    const unsigned rswz = (unsigned)((l15 & 7) << 4);
    const unsigned ra0  = (unsigned)(l15 * 128) + (((unsigned)(l4 * 16))      ^ rswz);
    const unsigned ra1  = (unsigned)(l15 * 128) + (((unsigned)(64 + l4 * 16)) ^ rswz);

    const int gwave = (int)((blockIdx.x * blockDim.x + tid) >> 6);
    const float* xp = x + (size_t)gwave * (TPW * 1024) + l4 * 64 + l15 * 4;
    float* op = out + gwave * (TPW * 16);

    // loads for one tile: 4x dwordx4, each 1KB dense across the wave
#define LOADSET(dst, ti)                                                  \
    {                                                                     \
        const float* q_ = xp + (ti) * 1024;                               \
        dst[0] = *reinterpret_cast<const float4*>(q_);                    \
        dst[1] = *reinterpret_cast<const float4*>(q_ + 256);              \
        dst[2] = *reinterpret_cast<const float4*>(q_ + 512);              \
        dst[3] = *reinterpret_cast<const float4*>(q_ + 768);              \
    }

#define STAGE(src, buf)                                                   \
    {                                                                     \
        unsigned char* nb_ = (buf);                                       \
        _Pragma("unroll")                                                 \
        for (int it = 0; it < 4; ++it) {                                  \
            const int r_ = it * 4 + l4;                                   \
            float4 v_ = src[it];                                          \
            short4 b_;                                                    \
            b_.x = f2bf(v_.x); b_.y = f2bf(v_.y);                         \
            b_.z = f2bf(v_.z); b_.w = f2bf(v_.w);                         \
            unsigned wa_ = (unsigned)(r_ * 128) +                         \
                (((unsigned)(l15 * 8)) ^ ((unsigned)((r_ & 7) << 4)));    \
            *reinterpret_cast<short4*>(nb_ + wa_) = b_;                   \
        }                                                                 \
    }

    // pend[(t)&1] holds the in-flight loads for tile t (t = i+1, i+2)
    float4 pend[2][4];
    float4 t0[4];
    LOADSET(t0, 0);
    LOADSET(pend[1], 1);
    STAGE(t0, wlds);              // waits only tile0's loads (older)

    #pragma unroll
    for (int i = 0; i < TPW; ++i) {
        // issue loads for tile i+2 (newest; 2 compute-phases of latency cover)
        if (i + 2 < TPW) LOADSET(pend[i & 1], i + 2);

        // ---- compute tile i
        unsigned char* cur = wlds + ((i & 1) ? 2048 : 0);
        bf16x8 b0 = *reinterpret_cast<const bf16x8*>(cur + ra0);  // k 0..31
        bf16x8 b1 = *reinterpret_cast<const bf16x8*>(cur + ra1);  // k 32..63

        f32x4 acc[4];
        #pragma unroll
        for (int t = 0; t < 4; ++t) {
            f32x4 z; z[0] = 0.f; z[1] = 0.f; z[2] = 0.f; z[3] = 0.f;
            z = __builtin_amdgcn_mfma_f32_16x16x32_bf16(wfrag[t][0], b0, z, 0, 0, 0);
            z = __builtin_amdgcn_mfma_f32_16x16x32_bf16(wfrag[t][1], b1, z, 0, 0, 0);
            acc[t] = z;
        }

        // epilogue: lane holds 16 hid-values of batch col l15.
        // exp(clamp(3z,±10)) == exp2(clamp(z*3*log2e, ±10*log2e))
        float sum = 0.f;
        #pragma unroll
        for (int t = 0; t < 4; ++t) {
            #pragma unroll
            for (int r = 0; r < 4; ++r) {
                float v = acc[t][r] * K_SCALE;
                v = fminf(fmaxf(v, -K_CLAMP), K_CLAMP);
                sum += exp2f(v);
            }
        }
        sum += __shfl_xor(sum, 16);
        sum += __shfl_xor(sum, 32);

        float lse = __logf(sum);
        float sp  = __logf(1.f + __expf(lse));          // softplus(lse)
        float e2  = __expf(2.f * sp);
        float th  = 1.f - 2.f / (e2 + 1.f);             // tanh(sp)
        float res = lse * th;

        // ---- stage tile i+1 (vmcnt-waits the OLDER pending set only;
        // issued a full iteration ago -> ~2 compute-phases of latency cover)
        if (i + 1 < TPW) {
            unsigned char* nxt = wlds + (((i + 1) & 1) ? 2048 : 0);
            STAGE(pend[(i + 1) & 1], nxt);
        }

        if (lane < 16) op[i * 16 + l15] = res;
    }
#undef LOADSET
#undef STAGE
}

extern "C" void kernel_launch(void* const* d_in, const int* in_sizes, int n_in,
                              void* d_out, int out_size, void* d_ws, size_t ws_size,
                              hipStream_t stream) {
    const float* x = (const float*)d_in[0];   // [BATCH, 64] fp32
    const float* W = (const float*)d_in[1];   // [64, 64]   fp32
    float* out = (float*)d_out;               // [BATCH] fp32 (B x 1)

    dim3 grid(2048), block(256);              // 8192 waves x 8 tiles
    hipLaunchKernelGGL(fused_lse_mish, grid, block, 0, stream, x, W, out);
}